// Round 12
// baseline (56.062 us; speedup 1.0000x reference)
//
#include <hip/hip_runtime.h>
#include <hip/hip_bf16.h>

#define EMB 64

typedef __attribute__((ext_vector_type(8))) short short8;
typedef __attribute__((ext_vector_type(8))) __bf16 bf16x8;
typedef __attribute__((ext_vector_type(4))) float f32x4;

__device__ inline f32x4 mfma16x16x32(short8 a, short8 b, f32x4 c) {
  return __builtin_amdgcn_mfma_f32_16x16x32_bf16(
      __builtin_bit_cast(bf16x8, a), __builtin_bit_cast(bf16x8, b), c, 0, 0, 0);
}

// Raw v_exp_f32 (2^x). OCML exp2f/__expf are multi-instr expansions (r2-r4).
#define EXP2_HW __builtin_amdgcn_exp2f
#define C5LOG2E 7.213475204444817f  // 5 * log2(e)

// Clears the 200,000-byte flag region (12,500 uint4).
__global__ __launch_bounds__(256) void clear_kernel(uint4* __restrict__ p) {
  const int i = blockIdx.x * 256 + threadIdx.x;
  if (i < 12500) p[i] = make_uint4(0u, 0u, 0u, 0u);
}

// prep: 512 blocks x 16 rows, 16-lane-group float4 layout (r11-proven).
__global__ __launch_bounds__(256) void prep_kernel(
    const int* __restrict__ user, const int* __restrict__ pos,
    const float* __restrict__ uw, const float* __restrict__ iw,
    __hip_bfloat16* __restrict__ u_bf, __hip_bfloat16* __restrict__ p_bf,
    unsigned char* __restrict__ uflag, unsigned char* __restrict__ iflag,
    float* __restrict__ up_p)
{
  const int tid  = threadIdx.x;
  const int wave = tid >> 6;
  const int lane = tid & 63;
  const int e    = lane & 15;
  const int row  = blockIdx.x * 16 + wave * 4 + (lane >> 4);

  const int uidx = user[row];
  const int pidx = pos[row];
  const float4 uv = *reinterpret_cast<const float4*>(&uw[(size_t)uidx * EMB + e * 4]);
  const float4 pv = *reinterpret_cast<const float4*>(&iw[(size_t)pidx * EMB + e * 4]);

  float us = uv.x*uv.x + uv.y*uv.y + uv.z*uv.z + uv.w*uv.w;
  float ps = pv.x*pv.x + pv.y*pv.y + pv.z*pv.z + pv.w*pv.w;
  #pragma unroll
  for (int off = 1; off < 16; off <<= 1) {
    us += __shfl_xor(us, off);
    ps += __shfl_xor(ps, off);
  }
  const float ur = 1.0f / fmaxf(sqrtf(us), 1e-12f);
  const float pr = 1.0f / fmaxf(sqrtf(ps), 1e-12f);
  const float4 un = make_float4(uv.x*ur, uv.y*ur, uv.z*ur, uv.w*ur);
  const float4 pn = make_float4(pv.x*pr, pv.y*pr, pv.z*pr, pv.w*pr);

  ushort4 ub, pb;
  ub.x = __bfloat16_as_ushort(__float2bfloat16(un.x));
  ub.y = __bfloat16_as_ushort(__float2bfloat16(un.y));
  ub.z = __bfloat16_as_ushort(__float2bfloat16(un.z));
  ub.w = __bfloat16_as_ushort(__float2bfloat16(un.w));
  pb.x = __bfloat16_as_ushort(__float2bfloat16(pn.x));
  pb.y = __bfloat16_as_ushort(__float2bfloat16(pn.y));
  pb.z = __bfloat16_as_ushort(__float2bfloat16(pn.z));
  pb.w = __bfloat16_as_ushort(__float2bfloat16(pn.w));
  *reinterpret_cast<ushort4*>(&u_bf[(size_t)row * EMB + e * 4]) = ub;
  *reinterpret_cast<ushort4*>(&p_bf[(size_t)row * EMB + e * 4]) = pb;

  float ip = un.x*pn.x + un.y*pn.y + un.z*pn.z + un.w*pn.w;
  #pragma unroll
  for (int off = 1; off < 16; off <<= 1) ip += __shfl_xor(ip, off);

  float upv = 0.0f;
  if (e == 0) {
    uflag[uidx] = 1;
    iflag[pidx] = 1;
    const float t = ip * C5LOG2E;
    upv = logf(EXP2_HW(t) + EXP2_HW(ip * t));  // log(exp(ip/T)+exp(ip^2/T))
  }
  upv += __shfl_xor(upv, 16);
  upv += __shfl_xor(upv, 32);

  __shared__ float sred[4];
  if (lane == 0) sred[wave] = upv;
  __syncthreads();
  if (tid == 0)
    up_p[blockIdx.x] = (sred[0] + sred[1]) + (sred[2] + sred[3]);
}

// 1024 blocks = 64 row-strips x 16 col-groups x 4 tiles. OCCUPANCY FIX:
// r11's acc[4][4]+a+b = ~160 VGPR -> 2 waves/SIMD, too few to hide exp/MFMA/L2
// latency (gemm stuck at ~30us vs ~10.5us issue floor). Now each 64x64 wave
// tile is processed as two 64x32 halves: acc[4][2]=32 VGPR, B double-buffered
// 16+16, total ~120 VGPR; __launch_bounds__(256,4) forces <=128 -> 4 waves/
// SIMD. Halves are software-pipelined (next B loads before current epilogue).
__global__ __launch_bounds__(256, 4) void gemm_kernel(
    const __hip_bfloat16* __restrict__ U, const __hip_bfloat16* __restrict__ P,
    float* __restrict__ dn_p)
{
  const int by  = blockIdx.x >> 4;          // [0,64)
  const int bx0 = (blockIdx.x & 15) << 2;   // 4 tiles -> 64 col-tiles
  const int wave = threadIdx.x >> 6;
  const int lane = threadIdx.x & 63;
  const int r0 = by * 128 + (wave >> 1) * 64;
  const int lrow = lane & 15;
  const int lk   = (lane >> 4) * 8;

  short8 a[4][2];
  #pragma unroll
  for (int i = 0; i < 4; ++i)
    #pragma unroll
    for (int kk = 0; kk < 2; ++kk)
      a[i][kk] = *reinterpret_cast<const short8*>(
          &U[(size_t)(r0 + i * 16 + lrow) * EMB + kk * 32 + lk]);

  float s0 = 0.0f, s1 = 0.0f, s2 = 0.0f, s3 = 0.0f;

  // (t,h) half-tile: cols [(bx0+t)*128 + (wave&1)*64 + h*32, +32)
  auto loadB = [&](int t, int h, short8 (&b)[2][2]) {
    const int c0 = (bx0 + t) * 128 + (wave & 1) * 64 + h * 32;
    #pragma unroll
    for (int j = 0; j < 2; ++j)
      #pragma unroll
      for (int kk = 0; kk < 2; ++kk)
        b[j][kk] = *reinterpret_cast<const short8*>(
            &P[(size_t)(c0 + j * 16 + lrow) * EMB + kk * 32 + lk]);
  };
  auto procHalf = [&](const short8 (&b)[2][2]) {
    f32x4 acc[4][2] = {};
    #pragma unroll
    for (int i = 0; i < 4; ++i)
      #pragma unroll
      for (int j = 0; j < 2; ++j) {
        acc[i][j] = mfma16x16x32(a[i][0], b[j][0], acc[i][j]);
        acc[i][j] = mfma16x16x32(a[i][1], b[j][1], acc[i][j]);
      }
    // exp(v/T)=2^(v*C); exp(v^2/T)=2^(v*(v*C)); |v|<=~1.
    #pragma unroll
    for (int i = 0; i < 4; ++i)
      #pragma unroll
      for (int j = 0; j < 2; ++j)
        #pragma unroll
        for (int r = 0; r < 4; ++r) {
          const float v  = acc[i][j][r];
          const float tt = v * C5LOG2E;
          if (j) { s2 += EXP2_HW(tt); s3 += EXP2_HW(v * tt); }
          else   { s0 += EXP2_HW(tt); s1 += EXP2_HW(v * tt); }
        }
  };

  short8 bA[2][2], bB[2][2];
  loadB(0, 0, bA);
  #pragma unroll 1
  for (int t = 0; t < 4; ++t) {
    loadB(t, 1, bB);              // next half's B in flight over half-0 compute
    procHalf(bA);
    loadB((t + 1) & 3, 0, bA);    // next tile's half-0 (t=3 harmlessly reloads 0)
    procHalf(bB);
  }

  float s = (s0 + s1) + (s2 + s3);
  #pragma unroll
  for (int off = 32; off; off >>= 1) s += __shfl_xor(s, off);

  __shared__ float sred[4];
  if (lane == 0) sred[wave] = s;
  __syncthreads();
  if (threadIdx.x == 0)
    dn_p[blockIdx.x] = (sred[0] + sred[1]) + (sred[2] + sred[3]);
}

// Single-block deterministic final reduction.
__global__ __launch_bounds__(1024) void finalize_kernel(
    const float* __restrict__ up_p, const float* __restrict__ dn_p,
    const uint4* __restrict__ uflag4, const uint4* __restrict__ iflag4,
    float* __restrict__ out)
{
  const int tid  = threadIdx.x;
  const int wave = tid >> 6;
  const int lane = tid & 63;

  float upv = (tid < 512) ? up_p[tid] : 0.0f;
  float dnv = dn_p[tid];                       // exactly 1024 partials
  int uc = 0, ic = 0;
  for (int i = tid; i < 6250; i += 1024) {     // 100000 B = 6250 * 16
    uint4 v = uflag4[i];
    uc += __popc(v.x) + __popc(v.y) + __popc(v.z) + __popc(v.w);
    uint4 w = iflag4[i];
    ic += __popc(w.x) + __popc(w.y) + __popc(w.z) + __popc(w.w);
  }

  #pragma unroll
  for (int off = 32; off; off >>= 1) {
    upv += __shfl_xor(upv, off);
    dnv += __shfl_xor(dnv, off);
    uc  += __shfl_xor(uc, off);
    ic  += __shfl_xor(ic, off);
  }

  __shared__ float sf[2][16];
  __shared__ int   si[2][16];
  if (lane == 0) { sf[0][wave] = upv; sf[1][wave] = dnv; si[0][wave] = uc; si[1][wave] = ic; }
  __syncthreads();
  if (tid == 0) {
    float usum = 0.0f, dsum = 0.0f; int nu = 0, ni = 0;
    #pragma unroll
    for (int w = 0; w < 16; ++w) {
      usum += sf[0][w]; dsum += sf[1][w]; nu += si[0][w]; ni += si[1][w];
    }
    out[0] = -(usum / 8192.0f);
    out[1] = logf(dsum / ((float)nu * (float)ni));
  }
}

extern "C" void kernel_launch(void* const* d_in, const int* in_sizes, int n_in,
                              void* d_out, int out_size, void* d_ws, size_t ws_size,
                              hipStream_t stream) {
  const int*   user = (const int*)d_in[0];
  const int*   pos  = (const int*)d_in[1];
  // d_in[2] = negative (unused by the reference loss)
  const float* uw   = (const float*)d_in[3];
  const float* iw   = (const float*)d_in[4];
  float* out = (float*)d_out;

  char* ws = (char*)d_ws;
  __hip_bfloat16* u_bf = (__hip_bfloat16*)(ws);
  __hip_bfloat16* p_bf = (__hip_bfloat16*)(ws + (1u << 20));
  uint4* flag4 = (uint4*)(ws + (2u << 20));              // 200,000 B
  unsigned char* uflag = (unsigned char*)flag4;
  unsigned char* iflag = uflag + 100000;
  float* up_p = (float*)(ws + (2u << 20) + 200704);      // 512
  float* dn_p = up_p + 512;                              // 1024

  clear_kernel<<<49, 256, 0, stream>>>(flag4);
  prep_kernel<<<512, 256, 0, stream>>>(user, pos, uw, iw, u_bf, p_bf,
                                       uflag, iflag, up_p);
  gemm_kernel<<<1024, 256, 0, stream>>>(u_bf, p_bf, dn_p);
  finalize_kernel<<<1, 1024, 0, stream>>>(up_p, dn_p,
                                          (const uint4*)uflag,
                                          (const uint4*)iflag, out);
}

// Round 13
// 42.557 us; speedup vs baseline: 1.3173x; 1.3173x over previous
//
#include <hip/hip_runtime.h>
#include <hip/hip_bf16.h>

#define EMB 64

typedef __attribute__((ext_vector_type(8))) short short8;
typedef __attribute__((ext_vector_type(8))) __bf16 bf16x8;
typedef __attribute__((ext_vector_type(4))) float f32x4;

__device__ inline f32x4 mfma16x16x32(short8 a, short8 b, f32x4 c) {
  return __builtin_amdgcn_mfma_f32_16x16x32_bf16(
      __builtin_bit_cast(bf16x8, a), __builtin_bit_cast(bf16x8, b), c, 0, 0, 0);
}

// Raw v_exp_f32 (2^x). OCML exp2f/__expf are multi-instr expansions (r2-r4).
#define EXP2_HW __builtin_amdgcn_exp2f
#define C5LOG2E 7.213475204444817f  // 5 * log2(e)

// Clears the 200,000-byte flag region (12,500 uint4).
__global__ __launch_bounds__(256) void clear_kernel(uint4* __restrict__ p) {
  const int i = blockIdx.x * 256 + threadIdx.x;
  if (i < 12500) p[i] = make_uint4(0u, 0u, 0u, 0u);
}

// prep: 512 blocks x 16 rows, 16-lane-group float4 layout (r11-proven).
__global__ __launch_bounds__(256) void prep_kernel(
    const int* __restrict__ user, const int* __restrict__ pos,
    const float* __restrict__ uw, const float* __restrict__ iw,
    __hip_bfloat16* __restrict__ u_bf, __hip_bfloat16* __restrict__ p_bf,
    unsigned char* __restrict__ uflag, unsigned char* __restrict__ iflag,
    float* __restrict__ up_p)
{
  const int tid  = threadIdx.x;
  const int wave = tid >> 6;
  const int lane = tid & 63;
  const int e    = lane & 15;
  const int row  = blockIdx.x * 16 + wave * 4 + (lane >> 4);

  const int uidx = user[row];
  const int pidx = pos[row];
  const float4 uv = *reinterpret_cast<const float4*>(&uw[(size_t)uidx * EMB + e * 4]);
  const float4 pv = *reinterpret_cast<const float4*>(&iw[(size_t)pidx * EMB + e * 4]);

  float us = uv.x*uv.x + uv.y*uv.y + uv.z*uv.z + uv.w*uv.w;
  float ps = pv.x*pv.x + pv.y*pv.y + pv.z*pv.z + pv.w*pv.w;
  #pragma unroll
  for (int off = 1; off < 16; off <<= 1) {
    us += __shfl_xor(us, off);
    ps += __shfl_xor(ps, off);
  }
  const float ur = 1.0f / fmaxf(sqrtf(us), 1e-12f);
  const float pr = 1.0f / fmaxf(sqrtf(ps), 1e-12f);
  const float4 un = make_float4(uv.x*ur, uv.y*ur, uv.z*ur, uv.w*ur);
  const float4 pn = make_float4(pv.x*pr, pv.y*pr, pv.z*pr, pv.w*pr);

  ushort4 ub, pb;
  ub.x = __bfloat16_as_ushort(__float2bfloat16(un.x));
  ub.y = __bfloat16_as_ushort(__float2bfloat16(un.y));
  ub.z = __bfloat16_as_ushort(__float2bfloat16(un.z));
  ub.w = __bfloat16_as_ushort(__float2bfloat16(un.w));
  pb.x = __bfloat16_as_ushort(__float2bfloat16(pn.x));
  pb.y = __bfloat16_as_ushort(__float2bfloat16(pn.y));
  pb.z = __bfloat16_as_ushort(__float2bfloat16(pn.z));
  pb.w = __bfloat16_as_ushort(__float2bfloat16(pn.w));
  *reinterpret_cast<ushort4*>(&u_bf[(size_t)row * EMB + e * 4]) = ub;
  *reinterpret_cast<ushort4*>(&p_bf[(size_t)row * EMB + e * 4]) = pb;

  float ip = un.x*pn.x + un.y*pn.y + un.z*pn.z + un.w*pn.w;
  #pragma unroll
  for (int off = 1; off < 16; off <<= 1) ip += __shfl_xor(ip, off);

  float upv = 0.0f;
  if (e == 0) {
    uflag[uidx] = 1;
    iflag[pidx] = 1;
    const float t = ip * C5LOG2E;
    upv = logf(EXP2_HW(t) + EXP2_HW(ip * t));  // log(exp(ip/T)+exp(ip^2/T))
  }
  upv += __shfl_xor(upv, 16);
  upv += __shfl_xor(upv, 32);

  __shared__ float sred[4];
  if (lane == 0) sred[wave] = upv;
  __syncthreads();
  if (tid == 0)
    up_p[blockIdx.x] = (sred[0] + sred[1]) + (sred[2] + sred[3]);
}

// 1024 blocks = 64 row-strips x 16 col-groups x 4 tiles. Half-tile structure
// (64x32 per step, acc[4][2]): live state ~115 VGPR. NO launch_bounds minimum:
// r12's (256,4) made the compiler cap at 64 VGPR and spill ~530B/thread to
// scratch (FETCH 26MB, WRITE 43MB, gemm 48us). With the natural ~128
// allocation we get 4 waves/SIMD (512-VGPR pool) and no spills — double r5's
// 2 waves/SIMD, to hide exp/MFMA/L2 latency. Halves software-pipelined.
__global__ __launch_bounds__(256) void gemm_kernel(
    const __hip_bfloat16* __restrict__ U, const __hip_bfloat16* __restrict__ P,
    float* __restrict__ dn_p)
{
  const int by  = blockIdx.x >> 4;          // [0,64)
  const int bx0 = (blockIdx.x & 15) << 2;   // 4 tiles -> 64 col-tiles
  const int wave = threadIdx.x >> 6;
  const int lane = threadIdx.x & 63;
  const int r0 = by * 128 + (wave >> 1) * 64;
  const int lrow = lane & 15;
  const int lk   = (lane >> 4) * 8;

  short8 a[4][2];
  #pragma unroll
  for (int i = 0; i < 4; ++i)
    #pragma unroll
    for (int kk = 0; kk < 2; ++kk)
      a[i][kk] = *reinterpret_cast<const short8*>(
          &U[(size_t)(r0 + i * 16 + lrow) * EMB + kk * 32 + lk]);

  float s0 = 0.0f, s1 = 0.0f, s2 = 0.0f, s3 = 0.0f;

  // (t,h) half-tile: cols [(bx0+t)*128 + (wave&1)*64 + h*32, +32)
  auto loadB = [&](int t, int h, short8 (&b)[2][2]) {
    const int c0 = (bx0 + t) * 128 + (wave & 1) * 64 + h * 32;
    #pragma unroll
    for (int j = 0; j < 2; ++j)
      #pragma unroll
      for (int kk = 0; kk < 2; ++kk)
        b[j][kk] = *reinterpret_cast<const short8*>(
            &P[(size_t)(c0 + j * 16 + lrow) * EMB + kk * 32 + lk]);
  };
  auto procHalf = [&](const short8 (&b)[2][2]) {
    f32x4 acc[4][2] = {};
    #pragma unroll
    for (int i = 0; i < 4; ++i)
      #pragma unroll
      for (int j = 0; j < 2; ++j) {
        acc[i][j] = mfma16x16x32(a[i][0], b[j][0], acc[i][j]);
        acc[i][j] = mfma16x16x32(a[i][1], b[j][1], acc[i][j]);
      }
    // exp(v/T)=2^(v*C); exp(v^2/T)=2^(v*(v*C)); |v|<=~1.
    #pragma unroll
    for (int i = 0; i < 4; ++i)
      #pragma unroll
      for (int j = 0; j < 2; ++j)
        #pragma unroll
        for (int r = 0; r < 4; ++r) {
          const float v  = acc[i][j][r];
          const float tt = v * C5LOG2E;
          if (j) { s2 += EXP2_HW(tt); s3 += EXP2_HW(v * tt); }
          else   { s0 += EXP2_HW(tt); s1 += EXP2_HW(v * tt); }
        }
  };

  short8 bA[2][2], bB[2][2];
  loadB(0, 0, bA);
  #pragma unroll 1
  for (int t = 0; t < 4; ++t) {
    loadB(t, 1, bB);              // next half's B in flight over half-0 compute
    procHalf(bA);
    loadB((t + 1) & 3, 0, bA);    // next tile's half-0 (t=3 harmlessly reloads 0)
    procHalf(bB);
  }

  float s = (s0 + s1) + (s2 + s3);
  #pragma unroll
  for (int off = 32; off; off >>= 1) s += __shfl_xor(s, off);

  __shared__ float sred[4];
  if (lane == 0) sred[wave] = s;
  __syncthreads();
  if (threadIdx.x == 0)
    dn_p[blockIdx.x] = (sred[0] + sred[1]) + (sred[2] + sred[3]);
}

// Single-block deterministic final reduction.
__global__ __launch_bounds__(1024) void finalize_kernel(
    const float* __restrict__ up_p, const float* __restrict__ dn_p,
    const uint4* __restrict__ uflag4, const uint4* __restrict__ iflag4,
    float* __restrict__ out)
{
  const int tid  = threadIdx.x;
  const int wave = tid >> 6;
  const int lane = tid & 63;

  float upv = (tid < 512) ? up_p[tid] : 0.0f;
  float dnv = dn_p[tid];                       // exactly 1024 partials
  int uc = 0, ic = 0;
  for (int i = tid; i < 6250; i += 1024) {     // 100000 B = 6250 * 16
    uint4 v = uflag4[i];
    uc += __popc(v.x) + __popc(v.y) + __popc(v.z) + __popc(v.w);
    uint4 w = iflag4[i];
    ic += __popc(w.x) + __popc(w.y) + __popc(w.z) + __popc(w.w);
  }

  #pragma unroll
  for (int off = 32; off; off >>= 1) {
    upv += __shfl_xor(upv, off);
    dnv += __shfl_xor(dnv, off);
    uc  += __shfl_xor(uc, off);
    ic  += __shfl_xor(ic, off);
  }

  __shared__ float sf[2][16];
  __shared__ int   si[2][16];
  if (lane == 0) { sf[0][wave] = upv; sf[1][wave] = dnv; si[0][wave] = uc; si[1][wave] = ic; }
  __syncthreads();
  if (tid == 0) {
    float usum = 0.0f, dsum = 0.0f; int nu = 0, ni = 0;
    #pragma unroll
    for (int w = 0; w < 16; ++w) {
      usum += sf[0][w]; dsum += sf[1][w]; nu += si[0][w]; ni += si[1][w];
    }
    out[0] = -(usum / 8192.0f);
    out[1] = logf(dsum / ((float)nu * (float)ni));
  }
}

extern "C" void kernel_launch(void* const* d_in, const int* in_sizes, int n_in,
                              void* d_out, int out_size, void* d_ws, size_t ws_size,
                              hipStream_t stream) {
  const int*   user = (const int*)d_in[0];
  const int*   pos  = (const int*)d_in[1];
  // d_in[2] = negative (unused by the reference loss)
  const float* uw   = (const float*)d_in[3];
  const float* iw   = (const float*)d_in[4];
  float* out = (float*)d_out;

  char* ws = (char*)d_ws;
  __hip_bfloat16* u_bf = (__hip_bfloat16*)(ws);
  __hip_bfloat16* p_bf = (__hip_bfloat16*)(ws + (1u << 20));
  uint4* flag4 = (uint4*)(ws + (2u << 20));              // 200,000 B
  unsigned char* uflag = (unsigned char*)flag4;
  unsigned char* iflag = uflag + 100000;
  float* up_p = (float*)(ws + (2u << 20) + 200704);      // 512
  float* dn_p = up_p + 512;                              // 1024

  clear_kernel<<<49, 256, 0, stream>>>(flag4);
  prep_kernel<<<512, 256, 0, stream>>>(user, pos, uw, iw, u_bf, p_bf,
                                       uflag, iflag, up_p);
  gemm_kernel<<<1024, 256, 0, stream>>>(u_bf, p_bf, dn_p);
  finalize_kernel<<<1, 1024, 0, stream>>>(up_p, dn_p,
                                          (const uint4*)uflag,
                                          (const uint4*)iflag, out);
}